// Round 1
// baseline (1040.931 us; speedup 1.0000x reference)
//
#include <hip/hip_runtime.h>
#include <cstddef>

// B=4, L=4096 (=64x64), d_model=512, d_inner=512, dt_rank=32, d_state=1
// All fp32. Pipeline:
//  1 gemm128<0>: xz = x @ in_proj_w.T  -> xin (ch-major, in d_out) + z (px-major, ws)
//  2 conv_silu : depthwise 3x3 SAME zero-pad + bias + silu -> xs (ch-major)
//  3 xdbl_k    : x_dbl / dts / delta / a / bb / Cs   (a->w4, bb->d_out, Cs)
//  4 scan_k    : h = a*h_prev + bb  (wave-parallel chunked scan, in-place on a)
//  5 sfconv_k  : 3 dilated edge-pad dwconvs (alpha folded) ; y = h*Cs + xs*Ds (in-place)
//  6 transpose : (B,D,L) -> (B,L,D) into xs buffer (xs dead)
//  7 ln_silu   : LayerNorm over D, * silu(z)  (in-place)
//  8 gemm128<1>: out = y @ out_proj_w.T -> d_out

// ---------------- fp32 GEMM, 128x128 tile, BK=16, 8x8 micro ----------------
template<int MODE> // 0: in_proj (split writes xin ch-major / z px-major), 1: plain out
__global__ __launch_bounds__(256)
void gemm128(const float* __restrict__ A, const float* __restrict__ Bw,
             float* __restrict__ o1, float* __restrict__ o2)
{
  __shared__ float As[16][132];
  __shared__ float Bs[16][132];
  const int K = 512;
  int tid = threadIdx.x;
  int row0 = blockIdx.y * 128;
  int n0   = blockIdx.x * 128;
  int lr = tid >> 2;            // 0..63
  int lc = (tid & 3) << 2;      // 0,4,8,12
  int tx = tid & 15, ty = tid >> 4;
  // MODE0: lanes along M (coalesced ch-major xin writes); MODE1: lanes along N
  int mo = (MODE == 0) ? (tx << 2) : (ty << 2);
  int no = (MODE == 0) ? (ty << 2) : (tx << 2);

  float acc[8][8];
#pragma unroll
  for (int i = 0; i < 8; i++)
#pragma unroll
    for (int j = 0; j < 8; j++) acc[i][j] = 0.f;

  const float* Ap0 = A  + (size_t)(row0 + lr) * K + lc;
  const float* Ap1 = A  + (size_t)(row0 + lr + 64) * K + lc;
  const float* Bp0 = Bw + (size_t)(n0 + lr) * K + lc;
  const float* Bp1 = Bw + (size_t)(n0 + lr + 64) * K + lc;

  for (int kt = 0; kt < K; kt += 16) {
    float4 a0 = *(const float4*)(Ap0 + kt);
    float4 a1 = *(const float4*)(Ap1 + kt);
    float4 b0 = *(const float4*)(Bp0 + kt);
    float4 b1 = *(const float4*)(Bp1 + kt);
    __syncthreads();
    As[lc+0][lr] = a0.x; As[lc+1][lr] = a0.y; As[lc+2][lr] = a0.z; As[lc+3][lr] = a0.w;
    As[lc+0][lr+64] = a1.x; As[lc+1][lr+64] = a1.y; As[lc+2][lr+64] = a1.z; As[lc+3][lr+64] = a1.w;
    Bs[lc+0][lr] = b0.x; Bs[lc+1][lr] = b0.y; Bs[lc+2][lr] = b0.z; Bs[lc+3][lr] = b0.w;
    Bs[lc+0][lr+64] = b1.x; Bs[lc+1][lr+64] = b1.y; Bs[lc+2][lr+64] = b1.z; Bs[lc+3][lr+64] = b1.w;
    __syncthreads();
#pragma unroll
    for (int kk = 0; kk < 16; kk++) {
      float4 x0 = *(const float4*)&As[kk][mo];
      float4 x1 = *(const float4*)&As[kk][mo + 64];
      float4 y0 = *(const float4*)&Bs[kk][no];
      float4 y1 = *(const float4*)&Bs[kk][no + 64];
      float am[8]  = {x0.x,x0.y,x0.z,x0.w,x1.x,x1.y,x1.z,x1.w};
      float bn_[8] = {y0.x,y0.y,y0.z,y0.w,y1.x,y1.y,y1.z,y1.w};
#pragma unroll
      for (int i = 0; i < 8; i++)
#pragma unroll
        for (int j = 0; j < 8; j++) acc[i][j] = fmaf(am[i], bn_[j], acc[i][j]);
    }
  }

  if (MODE == 0) {
    int b  = row0 >> 12;
    int l0 = row0 & 4095;
    if (n0 < 512) {
      // xin channel-major: o1[(b*512+c)*4096 + l], float4 along l
#pragma unroll
      for (int j = 0; j < 8; j++) {
        int c = n0 + no + (j & 3) + ((j >> 2) << 6);
#pragma unroll
        for (int g = 0; g < 2; g++) {
          float4 v = make_float4(acc[g*4+0][j], acc[g*4+1][j], acc[g*4+2][j], acc[g*4+3][j]);
          *(float4*)&o1[((size_t)(b * 512 + c)) * 4096 + l0 + mo + g * 64] = v;
        }
      }
    } else {
      // z pixel-major: o2[(b*4096+l)*512 + c'], float4 along c
#pragma unroll
      for (int i = 0; i < 8; i++) {
        int m = mo + (i & 3) + ((i >> 2) << 6);
        int l = l0 + m;
#pragma unroll
        for (int g = 0; g < 2; g++) {
          float4 v = make_float4(acc[i][g*4+0], acc[i][g*4+1], acc[i][g*4+2], acc[i][g*4+3]);
          *(float4*)&o2[((size_t)(b * 4096 + l)) * 512 + (n0 - 512) + no + g * 64] = v;
        }
      }
    }
  } else {
    // out px-major: o1[row*512 + n], lanes along n -> coalesced
#pragma unroll
    for (int i = 0; i < 8; i++) {
      int m = mo + (i & 3) + ((i >> 2) << 6);
#pragma unroll
      for (int g = 0; g < 2; g++) {
        float4 v = make_float4(acc[i][g*4+0], acc[i][g*4+1], acc[i][g*4+2], acc[i][g*4+3]);
        *(float4*)&o1[(size_t)(row0 + m) * 512 + n0 + no + g * 64] = v;
      }
    }
  }
}

// ---------------- depthwise 3x3 SAME (zero pad) + bias + silu ----------------
__global__ __launch_bounds__(256)
void conv_silu_k(const float* __restrict__ xin, const float* __restrict__ w,
                 const float* __restrict__ bias, float* __restrict__ xs)
{
  __shared__ float t[64][65];
  int plane = blockIdx.x;          // b*512 + d
  int d = plane & 511;
  int tid = threadIdx.x;
  const float* src = xin + (size_t)plane * 4096;
#pragma unroll
  for (int i = 0; i < 16; i++) {
    int idx = tid + i * 256;
    t[idx >> 6][idx & 63] = src[idx];
  }
  float wv[9];
#pragma unroll
  for (int j = 0; j < 9; j++) wv[j] = w[d * 9 + j];
  float bv = bias[d];
  __syncthreads();
  float* dst = xs + (size_t)plane * 4096;
#pragma unroll
  for (int i = 0; i < 16; i++) {
    int idx = tid + i * 256;
    int y = idx >> 6, x = idx & 63;
    float s = bv;
#pragma unroll
    for (int u = 0; u < 3; u++)
#pragma unroll
      for (int v = 0; v < 3; v++) {
        int yy = y + u - 1, xx = x + v - 1;
        if (yy >= 0 && yy < 64 && xx >= 0 && xx < 64)
          s = fmaf(wv[u * 3 + v], t[yy][xx], s);
      }
    dst[idx] = s * (1.f / (1.f + __expf(-s)));   // silu
  }
}

// ---------------- x_dbl -> dts -> delta, a, bb, Cs (one pixel per thread) ----
__global__ __launch_bounds__(64)
void xdbl_k(const float* __restrict__ xs, const float* __restrict__ xpw,
            const float* __restrict__ dtw, const float* __restrict__ dtb,
            const float* __restrict__ A_logs, float* __restrict__ a_buf,
            float* __restrict__ bb_buf, float* __restrict__ Cs)
{
  int gid = blockIdx.x * 64 + threadIdx.x;   // 0..16383  (b*4096 + l)
  int b = gid >> 12;
  int l = gid & 4095;
  float acc[34];
#pragma unroll
  for (int k = 0; k < 34; k++) acc[k] = 0.f;
  const float* xp = xs + (size_t)b * 512 * 4096 + l;
#pragma unroll 8
  for (int d = 0; d < 512; d++) {
    float v = xp[(size_t)d * 4096];
#pragma unroll
    for (int k = 0; k < 34; k++) acc[k] = fmaf(xpw[k * 512 + d], v, acc[k]);
  }
  float Bsl = acc[32];
  Cs[gid] = acc[33];
#pragma unroll 4
  for (int d = 0; d < 512; d++) {
    float s = dtb[d];
#pragma unroll
    for (int r = 0; r < 32; r++) s = fmaf(dtw[d * 32 + r], acc[r], s);
    float delta = (s > 15.f) ? s : log1pf(__expf(s));     // softplus
    float Ad = -__expf(A_logs[d]);
    float av = __expf(delta * Ad);
    float v = xp[(size_t)d * 4096];
    size_t o = ((size_t)(b * 512 + d)) * 4096 + l;
    a_buf[o] = av;
    bb_buf[o] = delta * Bsl * v;
  }
}

// ---------------- first-order scan, one wave per (b,d) row ------------------
__global__ __launch_bounds__(256)
void scan_k(float* __restrict__ a_h, const float* __restrict__ bb)
{
  int wid = threadIdx.x >> 6, lane = threadIdx.x & 63;
  int row = blockIdx.x * 4 + wid;            // 0..2047
  size_t base = (size_t)row * 4096;
  float s = 0.f;
  for (int c = 0; c < 64; c++) {
    int l = c * 64 + lane;
    float Av = a_h[base + l];
    float Bv = bb[base + l];
#pragma unroll
    for (int off = 1; off < 64; off <<= 1) {
      float Ap = __shfl_up(Av, off);
      float Bp = __shfl_up(Bv, off);
      if (lane >= off) { Bv = fmaf(Av, Bp, Bv); Av *= Ap; }
    }
    float h = fmaf(Av, s, Bv);
    a_h[base + l] = h;
    s = __shfl(h, 63);
  }
}

// ---- 3 dilated edge-pad depthwise convs (alpha folded) + y = h*Cs + xs*Ds --
__global__ __launch_bounds__(256)
void sfconv_k(float* __restrict__ h, const float* __restrict__ k1,
              const float* __restrict__ k2, const float* __restrict__ k3,
              const float* __restrict__ alpha, const float* __restrict__ Cs,
              const float* __restrict__ xs, const float* __restrict__ Ds)
{
  __shared__ float t[64][65];
  int plane = blockIdx.x;
  int d = plane & 511;
  int b = plane >> 9;
  int tid = threadIdx.x;
  float* hp = h + (size_t)plane * 4096;
#pragma unroll
  for (int i = 0; i < 16; i++) {
    int idx = tid + i * 256;
    t[idx >> 6][idx & 63] = hp[idx];
  }
  float wv[3][9];
  float a0 = alpha[0], a1 = alpha[1], a2 = alpha[2];
#pragma unroll
  for (int j = 0; j < 9; j++) {
    wv[0][j] = a0 * k1[d * 9 + j];
    wv[1][j] = a1 * k2[d * 9 + j];
    wv[2][j] = a2 * k3[d * 9 + j];
  }
  float Dv = Ds[d];
  const float* xsp = xs + (size_t)plane * 4096;
  const float* Csp = Cs + b * 4096;
  __syncthreads();
#pragma unroll
  for (int i = 0; i < 16; i++) {
    int idx = tid + i * 256;
    int y = idx >> 6, x = idx & 63;
    float s = 0.f;
#pragma unroll
    for (int dil = 1; dil <= 3; dil++)
#pragma unroll
      for (int u = 0; u < 3; u++)
#pragma unroll
        for (int v = 0; v < 3; v++) {
          int yy = y + (u - 1) * dil; yy = yy < 0 ? 0 : (yy > 63 ? 63 : yy);
          int xx = x + (v - 1) * dil; xx = xx < 0 ? 0 : (xx > 63 ? 63 : xx);
          s = fmaf(wv[dil - 1][u * 3 + v], t[yy][xx], s);
        }
    hp[idx] = fmaf(s, Csp[idx], xsp[idx] * Dv);   // in-place (reads from LDS)
  }
}

// ---------------- transpose (B,D,L) -> (B,L,D) -------------------------------
__global__ __launch_bounds__(256)
void transpose_k(const float* __restrict__ src, float* __restrict__ dst)
{
  __shared__ float t[64][65];
  int l0 = blockIdx.x * 64;
  int d0 = blockIdx.y * 64;
  int b  = blockIdx.z;
  int tid = threadIdx.x;
  int c = tid & 63, r4 = tid >> 6;
#pragma unroll
  for (int i = 0; i < 16; i++) {
    int r = r4 + i * 4;
    t[r][c] = src[((size_t)(b * 512 + d0 + r)) * 4096 + l0 + c];
  }
  __syncthreads();
#pragma unroll
  for (int i = 0; i < 16; i++) {
    int r = r4 + i * 4;   // l offset
    dst[((size_t)(b * 4096 + l0 + r)) * 512 + d0 + c] = t[c][r];
  }
}

// ---------------- LayerNorm over D + silu(z) gate (in-place) ----------------
__global__ __launch_bounds__(256)
void ln_silu_k(float* __restrict__ y, const float* __restrict__ z,
               const float* __restrict__ lw, const float* __restrict__ lb)
{
  int wid = threadIdx.x >> 6, lane = threadIdx.x & 63;
  int pix = blockIdx.x * 4 + wid;            // 0..16383
  float* yp = y + (size_t)pix * 512;
  const float* zp = z + (size_t)pix * 512;
  float4 v0 = *(float4*)&yp[lane * 8];
  float4 v1 = *(float4*)&yp[lane * 8 + 4];
  float vv[8] = {v0.x,v0.y,v0.z,v0.w,v1.x,v1.y,v1.z,v1.w};
  float sum = 0.f;
#pragma unroll
  for (int j = 0; j < 8; j++) sum += vv[j];
#pragma unroll
  for (int off = 1; off < 64; off <<= 1) sum += __shfl_xor(sum, off);
  float mu = sum * (1.f / 512.f);
  float q = 0.f;
#pragma unroll
  for (int j = 0; j < 8; j++) { float dd = vv[j] - mu; q += dd * dd; }
#pragma unroll
  for (int off = 1; off < 64; off <<= 1) q += __shfl_xor(q, off);
  float rstd = rsqrtf(q * (1.f / 512.f) + 1e-5f);
  float4 z0 = *(const float4*)&zp[lane * 8];
  float4 z1 = *(const float4*)&zp[lane * 8 + 4];
  float zz[8] = {z0.x,z0.y,z0.z,z0.w,z1.x,z1.y,z1.z,z1.w};
  float out[8];
#pragma unroll
  for (int j = 0; j < 8; j++) {
    int dch = lane * 8 + j;
    float val = (vv[j] - mu) * rstd * lw[dch] + lb[dch];
    float zv = zz[j];
    out[j] = val * (zv * (1.f / (1.f + __expf(-zv))));
  }
  *(float4*)&yp[lane * 8]     = make_float4(out[0], out[1], out[2], out[3]);
  *(float4*)&yp[lane * 8 + 4] = make_float4(out[4], out[5], out[6], out[7]);
}

extern "C" void kernel_launch(void* const* d_in, const int* in_sizes, int n_in,
                              void* d_out, int out_size, void* d_ws, size_t ws_size,
                              hipStream_t stream)
{
  const float* x    = (const float*)d_in[0];
  const float* win  = (const float*)d_in[1];
  const float* cw   = (const float*)d_in[2];
  const float* cb   = (const float*)d_in[3];
  const float* xpw  = (const float*)d_in[4];
  const float* dtw  = (const float*)d_in[5];
  const float* dtb  = (const float*)d_in[6];
  const float* alog = (const float*)d_in[7];
  const float* Dsv  = (const float*)d_in[8];
  const float* k1   = (const float*)d_in[9];
  const float* k2   = (const float*)d_in[10];
  const float* k3   = (const float*)d_in[11];
  const float* alp  = (const float*)d_in[12];
  const float* lw   = (const float*)d_in[13];
  const float* lb   = (const float*)d_in[14];
  const float* wout = (const float*)d_in[15];
  float* out = (float*)d_out;

  const size_t NP = (size_t)4 * 512 * 4096;   // 8,388,608 elems per (B,D,L) buffer
  float* ws = (float*)d_ws;
  float* xs  = ws;                 // xs  (later reused as y_t / normalized y)
  float* zb  = ws + NP;            // z, pixel-major
  float* w4  = ws + 2 * NP;        // a -> h -> ypre
  float* Csb = ws + 3 * NP;        // (B,L)
  // d_out doubles as scratch: xin (stage1-2) then bb (stage3-4), final out (stage8)

  gemm128<0><<<dim3(8, 128), 256, 0, stream>>>(x, win, out, zb);          // xin->d_out, z->zb
  conv_silu_k<<<2048, 256, 0, stream>>>(out, cw, cb, xs);                 // xs
  xdbl_k<<<256, 64, 0, stream>>>(xs, xpw, dtw, dtb, alog, w4, out, Csb);  // a->w4, bb->d_out
  scan_k<<<512, 256, 0, stream>>>(w4, out);                               // h in-place in w4
  sfconv_k<<<2048, 256, 0, stream>>>(w4, k1, k2, k3, alp, Csb, xs, Dsv);  // ypre in-place
  transpose_k<<<dim3(64, 8, 4), 256, 0, stream>>>(w4, xs);                // y_t -> xs buffer
  ln_silu_k<<<4096, 256, 0, stream>>>(xs, zb, lw, lb);                    // in-place
  gemm128<1><<<dim3(4, 128), 256, 0, stream>>>(xs, wout, out, nullptr);   // final
}

// Round 2
// 523.563 us; speedup vs baseline: 1.9882x; 1.9882x over previous
//
#include <hip/hip_runtime.h>
#include <cstddef>

// B=4, L=4096 (=64x64), d_model=512, d_inner=512, dt_rank=32, d_state=1
// All fp32. Pipeline:
//  1 gemm128<0>   : xz = x @ in_proj_w.T -> xin (ch-major, d_out) + z (px-major, ws)
//  2 conv_silu    : depthwise 3x3 SAME zero-pad + bias + silu -> xs (ch-major)
//  3a xdbl_part   : partial x_dbl GEMM (8-way K split) -> partial (d_out, xin dead)
//  3b xdbl_reduce : sum partials -> xdbl_r (34 x 16384, ws)
//  3c delta_ab    : dts -> delta -> a (w4), bb (d_out, partial dead)
//  4 scan_k       : h = a*h_prev + bb (wave-parallel chunked scan, in-place on a)
//  5 sfconv_k     : 3 dilated edge-pad dwconvs (alpha folded); y = h*Cs + xs*Ds
//  6 transpose    : (B,D,L) -> (B,L,D) into xs buffer (xs dead)
//  7 ln_silu      : LayerNorm over D, * silu(z) (in-place)
//  8 gemm128<1>   : out = y @ out_proj_w.T -> d_out

// ---------------- fp32 GEMM, 128x128 tile, BK=16, 8x8 micro ----------------
template<int MODE> // 0: in_proj (split writes xin ch-major / z px-major), 1: plain out
__global__ __launch_bounds__(256)
void gemm128(const float* __restrict__ A, const float* __restrict__ Bw,
             float* __restrict__ o1, float* __restrict__ o2)
{
  __shared__ float As[16][132];
  __shared__ float Bs[16][132];
  const int K = 512;
  int tid = threadIdx.x;
  int row0 = blockIdx.y * 128;
  int n0   = blockIdx.x * 128;
  int lr = tid >> 2;            // 0..63
  int lc = (tid & 3) << 2;      // 0,4,8,12
  int tx = tid & 15, ty = tid >> 4;
  int mo = (MODE == 0) ? (tx << 2) : (ty << 2);
  int no = (MODE == 0) ? (ty << 2) : (tx << 2);

  float acc[8][8];
#pragma unroll
  for (int i = 0; i < 8; i++)
#pragma unroll
    for (int j = 0; j < 8; j++) acc[i][j] = 0.f;

  const float* Ap0 = A  + (size_t)(row0 + lr) * K + lc;
  const float* Ap1 = A  + (size_t)(row0 + lr + 64) * K + lc;
  const float* Bp0 = Bw + (size_t)(n0 + lr) * K + lc;
  const float* Bp1 = Bw + (size_t)(n0 + lr + 64) * K + lc;

  for (int kt = 0; kt < K; kt += 16) {
    float4 a0 = *(const float4*)(Ap0 + kt);
    float4 a1 = *(const float4*)(Ap1 + kt);
    float4 b0 = *(const float4*)(Bp0 + kt);
    float4 b1 = *(const float4*)(Bp1 + kt);
    __syncthreads();
    As[lc+0][lr] = a0.x; As[lc+1][lr] = a0.y; As[lc+2][lr] = a0.z; As[lc+3][lr] = a0.w;
    As[lc+0][lr+64] = a1.x; As[lc+1][lr+64] = a1.y; As[lc+2][lr+64] = a1.z; As[lc+3][lr+64] = a1.w;
    Bs[lc+0][lr] = b0.x; Bs[lc+1][lr] = b0.y; Bs[lc+2][lr] = b0.z; Bs[lc+3][lr] = b0.w;
    Bs[lc+0][lr+64] = b1.x; Bs[lc+1][lr+64] = b1.y; Bs[lc+2][lr+64] = b1.z; Bs[lc+3][lr+64] = b1.w;
    __syncthreads();
#pragma unroll
    for (int kk = 0; kk < 16; kk++) {
      float4 x0 = *(const float4*)&As[kk][mo];
      float4 x1 = *(const float4*)&As[kk][mo + 64];
      float4 y0 = *(const float4*)&Bs[kk][no];
      float4 y1 = *(const float4*)&Bs[kk][no + 64];
      float am[8]  = {x0.x,x0.y,x0.z,x0.w,x1.x,x1.y,x1.z,x1.w};
      float bn_[8] = {y0.x,y0.y,y0.z,y0.w,y1.x,y1.y,y1.z,y1.w};
#pragma unroll
      for (int i = 0; i < 8; i++)
#pragma unroll
        for (int j = 0; j < 8; j++) acc[i][j] = fmaf(am[i], bn_[j], acc[i][j]);
    }
  }

  if (MODE == 0) {
    int b  = row0 >> 12;
    int l0 = row0 & 4095;
    if (n0 < 512) {
#pragma unroll
      for (int j = 0; j < 8; j++) {
        int c = n0 + no + (j & 3) + ((j >> 2) << 6);
#pragma unroll
        for (int g = 0; g < 2; g++) {
          float4 v = make_float4(acc[g*4+0][j], acc[g*4+1][j], acc[g*4+2][j], acc[g*4+3][j]);
          *(float4*)&o1[((size_t)(b * 512 + c)) * 4096 + l0 + mo + g * 64] = v;
        }
      }
    } else {
#pragma unroll
      for (int i = 0; i < 8; i++) {
        int m = mo + (i & 3) + ((i >> 2) << 6);
        int l = l0 + m;
#pragma unroll
        for (int g = 0; g < 2; g++) {
          float4 v = make_float4(acc[i][g*4+0], acc[i][g*4+1], acc[i][g*4+2], acc[i][g*4+3]);
          *(float4*)&o2[((size_t)(b * 4096 + l)) * 512 + (n0 - 512) + no + g * 64] = v;
        }
      }
    }
  } else {
#pragma unroll
    for (int i = 0; i < 8; i++) {
      int m = mo + (i & 3) + ((i >> 2) << 6);
#pragma unroll
      for (int g = 0; g < 2; g++) {
        float4 v = make_float4(acc[i][g*4+0], acc[i][g*4+1], acc[i][g*4+2], acc[i][g*4+3]);
        *(float4*)&o1[(size_t)(row0 + m) * 512 + n0 + no + g * 64] = v;
      }
    }
  }
}

// ---------------- depthwise 3x3 SAME (zero pad) + bias + silu ----------------
__global__ __launch_bounds__(256)
void conv_silu_k(const float* __restrict__ xin, const float* __restrict__ w,
                 const float* __restrict__ bias, float* __restrict__ xs)
{
  __shared__ float t[64][65];
  int plane = blockIdx.x;          // b*512 + d
  int d = plane & 511;
  int tid = threadIdx.x;
  const float* src = xin + (size_t)plane * 4096;
#pragma unroll
  for (int i = 0; i < 16; i++) {
    int idx = tid + i * 256;
    t[idx >> 6][idx & 63] = src[idx];
  }
  float wv[9];
#pragma unroll
  for (int j = 0; j < 9; j++) wv[j] = w[d * 9 + j];
  float bv = bias[d];
  __syncthreads();
  float* dst = xs + (size_t)plane * 4096;
#pragma unroll
  for (int i = 0; i < 16; i++) {
    int idx = tid + i * 256;
    int y = idx >> 6, x = idx & 63;
    float s = bv;
#pragma unroll
    for (int u = 0; u < 3; u++)
#pragma unroll
      for (int v = 0; v < 3; v++) {
        int yy = y + u - 1, xx = x + v - 1;
        if (yy >= 0 && yy < 64 && xx >= 0 && xx < 64)
          s = fmaf(wv[u * 3 + v], t[yy][xx], s);
      }
    dst[idx] = s * (1.f / (1.f + __expf(-s)));   // silu
  }
}

// ------- 3a: partial x_dbl GEMM: 8-way split over d; one pixel per thread ---
// partial[(split*34 + k)*16384 + p] = sum_{d in chunk} xpw[k][d] * xs[b][d][l]
__global__ __launch_bounds__(256)
void xdbl_part_k(const float* __restrict__ xs, const float* __restrict__ xpw,
                 float* __restrict__ partial)
{
  __shared__ float sw[34 * 64];    // xpw chunk, [k][dd]
  int tid = threadIdx.x;
  int p  = blockIdx.x * 256 + tid;   // pixel 0..16383 (b*4096+l)
  int d0 = blockIdx.y * 64;
  int b = p >> 12, l = p & 4095;
  for (int i = tid; i < 34 * 64; i += 256) {
    int k = i >> 6, dd = i & 63;
    sw[i] = xpw[k * 512 + d0 + dd];
  }
  __syncthreads();
  float acc[34];
#pragma unroll
  for (int k = 0; k < 34; k++) acc[k] = 0.f;
  const float* xp = xs + (size_t)(b * 512 + d0) * 4096 + l;
#pragma unroll 4
  for (int dd = 0; dd < 64; dd++) {
    float v = xp[(size_t)dd * 4096];
#pragma unroll
    for (int k = 0; k < 34; k++) acc[k] = fmaf(sw[k * 64 + dd], v, acc[k]);
  }
  float* op = partial + (size_t)blockIdx.y * 34 * 16384 + p;
#pragma unroll
  for (int k = 0; k < 34; k++) op[(size_t)k * 16384] = acc[k];
}

// ------- 3b: reduce 8 partials -> xdbl_r[34][16384] -------------------------
__global__ __launch_bounds__(256)
void xdbl_reduce_k(const float* __restrict__ partial, float* __restrict__ xdbl_r)
{
  int gid = blockIdx.x * 256 + threadIdx.x;   // 0 .. 34*16384-1
  float s = 0.f;
#pragma unroll
  for (int sp = 0; sp < 8; sp++) s += partial[(size_t)sp * 34 * 16384 + gid];
  xdbl_r[gid] = s;
}

// ------- 3c: dts -> delta -> a, bb. LDS-stage xdbl rows for a 256-px tile ---
__global__ __launch_bounds__(256)
void delta_ab_k(const float* __restrict__ xdbl_r, const float* __restrict__ xs,
                const float* __restrict__ dtw, const float* __restrict__ dtb,
                const float* __restrict__ A_logs, float* __restrict__ a_buf,
                float* __restrict__ bb_buf)
{
  __shared__ float sm[33][256];    // rows 0..31 = dt-rank, row 32 = Bs
  int tid = threadIdx.x;
  int l0 = blockIdx.x * 256;       // l tile within batch
  int d0 = blockIdx.y * 64;        // d chunk
  int b  = blockIdx.z;
  int p0 = b * 4096 + l0;
#pragma unroll
  for (int k = 0; k < 33; k++) sm[k][tid] = xdbl_r[k * 16384 + p0 + tid];
  __syncthreads();
  float Bsl = sm[32][tid];
  const float* xp = xs + (size_t)(b * 512 + d0) * 4096 + l0 + tid;
#pragma unroll 2
  for (int dd = 0; dd < 64; dd++) {
    int d = d0 + dd;
    float s = dtb[d];
#pragma unroll
    for (int r = 0; r < 32; r++) s = fmaf(dtw[d * 32 + r], sm[r][tid], s);
    // softplus (stable)
    float delta = fmaxf(s, 0.f) + __logf(1.f + __expf(-fabsf(s)));
    float Ad = -__expf(A_logs[d]);
    float av = __expf(delta * Ad);
    float v = xp[(size_t)dd * 4096];
    size_t o = ((size_t)(b * 512 + d)) * 4096 + l0 + tid;
    a_buf[o] = av;
    bb_buf[o] = delta * Bsl * v;
  }
}

// ---------------- first-order scan, one wave per (b,d) row ------------------
__global__ __launch_bounds__(256)
void scan_k(float* __restrict__ a_h, const float* __restrict__ bb)
{
  int wid = threadIdx.x >> 6, lane = threadIdx.x & 63;
  int row = blockIdx.x * 4 + wid;            // 0..2047
  size_t base = (size_t)row * 4096;
  float s = 0.f;
  for (int c = 0; c < 64; c++) {
    int l = c * 64 + lane;
    float Av = a_h[base + l];
    float Bv = bb[base + l];
#pragma unroll
    for (int off = 1; off < 64; off <<= 1) {
      float Ap = __shfl_up(Av, off);
      float Bp = __shfl_up(Bv, off);
      if (lane >= off) { Bv = fmaf(Av, Bp, Bv); Av *= Ap; }
    }
    float h = fmaf(Av, s, Bv);
    a_h[base + l] = h;
    s = __shfl(h, 63);
  }
}

// ---- 3 dilated edge-pad depthwise convs (alpha folded) + y = h*Cs + xs*Ds --
__global__ __launch_bounds__(256)
void sfconv_k(float* __restrict__ h, const float* __restrict__ k1,
              const float* __restrict__ k2, const float* __restrict__ k3,
              const float* __restrict__ alpha, const float* __restrict__ Cs,
              const float* __restrict__ xs, const float* __restrict__ Ds)
{
  __shared__ float t[64][65];
  int plane = blockIdx.x;
  int d = plane & 511;
  int b = plane >> 9;
  int tid = threadIdx.x;
  float* hp = h + (size_t)plane * 4096;
#pragma unroll
  for (int i = 0; i < 16; i++) {
    int idx = tid + i * 256;
    t[idx >> 6][idx & 63] = hp[idx];
  }
  float wv[3][9];
  float a0 = alpha[0], a1 = alpha[1], a2 = alpha[2];
#pragma unroll
  for (int j = 0; j < 9; j++) {
    wv[0][j] = a0 * k1[d * 9 + j];
    wv[1][j] = a1 * k2[d * 9 + j];
    wv[2][j] = a2 * k3[d * 9 + j];
  }
  float Dv = Ds[d];
  const float* xsp = xs + (size_t)plane * 4096;
  const float* Csp = Cs + b * 4096;
  __syncthreads();
#pragma unroll
  for (int i = 0; i < 16; i++) {
    int idx = tid + i * 256;
    int y = idx >> 6, x = idx & 63;
    float s = 0.f;
#pragma unroll
    for (int dil = 1; dil <= 3; dil++)
#pragma unroll
      for (int u = 0; u < 3; u++)
#pragma unroll
        for (int v = 0; v < 3; v++) {
          int yy = y + (u - 1) * dil; yy = yy < 0 ? 0 : (yy > 63 ? 63 : yy);
          int xx = x + (v - 1) * dil; xx = xx < 0 ? 0 : (xx > 63 ? 63 : xx);
          s = fmaf(wv[dil - 1][u * 3 + v], t[yy][xx], s);
        }
    hp[idx] = fmaf(s, Csp[idx], xsp[idx] * Dv);   // in-place (reads from LDS)
  }
}

// ---------------- transpose (B,D,L) -> (B,L,D) -------------------------------
__global__ __launch_bounds__(256)
void transpose_k(const float* __restrict__ src, float* __restrict__ dst)
{
  __shared__ float t[64][65];
  int l0 = blockIdx.x * 64;
  int d0 = blockIdx.y * 64;
  int b  = blockIdx.z;
  int tid = threadIdx.x;
  int c = tid & 63, r4 = tid >> 6;
#pragma unroll
  for (int i = 0; i < 16; i++) {
    int r = r4 + i * 4;
    t[r][c] = src[((size_t)(b * 512 + d0 + r)) * 4096 + l0 + c];
  }
  __syncthreads();
#pragma unroll
  for (int i = 0; i < 16; i++) {
    int r = r4 + i * 4;   // l offset
    dst[((size_t)(b * 4096 + l0 + r)) * 512 + d0 + c] = t[c][r];
  }
}

// ---------------- LayerNorm over D + silu(z) gate (in-place) ----------------
__global__ __launch_bounds__(256)
void ln_silu_k(float* __restrict__ y, const float* __restrict__ z,
               const float* __restrict__ lw, const float* __restrict__ lb)
{
  int wid = threadIdx.x >> 6, lane = threadIdx.x & 63;
  int pix = blockIdx.x * 4 + wid;            // 0..16383
  float* yp = y + (size_t)pix * 512;
  const float* zp = z + (size_t)pix * 512;
  float4 v0 = *(float4*)&yp[lane * 8];
  float4 v1 = *(float4*)&yp[lane * 8 + 4];
  float vv[8] = {v0.x,v0.y,v0.z,v0.w,v1.x,v1.y,v1.z,v1.w};
  float sum = 0.f;
#pragma unroll
  for (int j = 0; j < 8; j++) sum += vv[j];
#pragma unroll
  for (int off = 1; off < 64; off <<= 1) sum += __shfl_xor(sum, off);
  float mu = sum * (1.f / 512.f);
  float q = 0.f;
#pragma unroll
  for (int j = 0; j < 8; j++) { float dd = vv[j] - mu; q += dd * dd; }
#pragma unroll
  for (int off = 1; off < 64; off <<= 1) q += __shfl_xor(q, off);
  float rstd = rsqrtf(q * (1.f / 512.f) + 1e-5f);
  float4 z0 = *(const float4*)&zp[lane * 8];
  float4 z1 = *(const float4*)&zp[lane * 8 + 4];
  float zz[8] = {z0.x,z0.y,z0.z,z0.w,z1.x,z1.y,z1.z,z1.w};
  float out[8];
#pragma unroll
  for (int j = 0; j < 8; j++) {
    int dch = lane * 8 + j;
    float val = (vv[j] - mu) * rstd * lw[dch] + lb[dch];
    float zv = zz[j];
    out[j] = val * (zv * (1.f / (1.f + __expf(-zv))));
  }
  *(float4*)&yp[lane * 8]     = make_float4(out[0], out[1], out[2], out[3]);
  *(float4*)&yp[lane * 8 + 4] = make_float4(out[4], out[5], out[6], out[7]);
}

extern "C" void kernel_launch(void* const* d_in, const int* in_sizes, int n_in,
                              void* d_out, int out_size, void* d_ws, size_t ws_size,
                              hipStream_t stream)
{
  const float* x    = (const float*)d_in[0];
  const float* win  = (const float*)d_in[1];
  const float* cw   = (const float*)d_in[2];
  const float* cb   = (const float*)d_in[3];
  const float* xpw  = (const float*)d_in[4];
  const float* dtw  = (const float*)d_in[5];
  const float* dtb  = (const float*)d_in[6];
  const float* alog = (const float*)d_in[7];
  const float* Dsv  = (const float*)d_in[8];
  const float* k1   = (const float*)d_in[9];
  const float* k2   = (const float*)d_in[10];
  const float* k3   = (const float*)d_in[11];
  const float* alp  = (const float*)d_in[12];
  const float* lw   = (const float*)d_in[13];
  const float* lb   = (const float*)d_in[14];
  const float* wout = (const float*)d_in[15];
  float* out = (float*)d_out;

  const size_t NP = (size_t)4 * 512 * 4096;   // 8,388,608 elems per (B,D,L) buffer
  float* ws = (float*)d_ws;
  float* xs     = ws;                 // xs (later reused as y_t / normalized y)
  float* zb     = ws + NP;            // z, pixel-major
  float* w4     = ws + 2 * NP;        // a -> h -> ypre
  float* xdbl_r = ws + 3 * NP;        // 34 x 16384
  // d_out doubles as scratch: xin (stages 1-2), partial (3a-3b), bb (3c-4), final out

  gemm128<0><<<dim3(8, 128), 256, 0, stream>>>(x, win, out, zb);            // xin, z
  conv_silu_k<<<2048, 256, 0, stream>>>(out, cw, cb, xs);                   // xs
  xdbl_part_k<<<dim3(64, 8), 256, 0, stream>>>(xs, xpw, out);               // partial->d_out
  xdbl_reduce_k<<<2176, 256, 0, stream>>>(out, xdbl_r);                     // xdbl_r
  delta_ab_k<<<dim3(16, 8, 4), 256, 0, stream>>>(xdbl_r, xs, dtw, dtb, alog,
                                                 w4, out);                  // a->w4, bb->d_out
  scan_k<<<512, 256, 0, stream>>>(w4, out);                                 // h in w4
  sfconv_k<<<2048, 256, 0, stream>>>(w4, k1, k2, k3, alp,
                                     xdbl_r + 33 * 16384, xs, Dsv);         // ypre in w4
  transpose_k<<<dim3(64, 8, 4), 256, 0, stream>>>(w4, xs);                  // y_t -> xs
  ln_silu_k<<<4096, 256, 0, stream>>>(xs, zb, lw, lb);                      // in-place
  gemm128<1><<<dim3(4, 128), 256, 0, stream>>>(xs, wout, out, nullptr);     // final
}

// Round 3
// 296.791 us; speedup vs baseline: 3.5073x; 1.7641x over previous
//
#include <hip/hip_runtime.h>
#include <cstddef>

// B=4, L=4096 (=64x64), d_model=512, d_inner=512, dt_rank=32, d_state=1
// GEMMs now run on MFMA via bf16x3 split (hi*hi + hi*lo + lo*hi), fp32 accum.
// Pipeline:
//  0a split x    -> Ahi/Alo (bf16, overlaid on w4 region)
//  0b split win  -> Whi/Wlo (overlaid on xs region)
//  1 gemm_mfma<0>: xz = x @ in_proj_w.T -> xin (ch-major, d_out) + z (px-major, zb)
//  2 conv_silu   : depthwise 3x3 SAME zero-pad + bias + silu -> xs
//  3a xdbl_part  : partial x_dbl GEMM (8-way K split) -> d_out (xin dead)
//  3b xdbl_reduce: sum partials -> xdbl_r
//  3c delta_ab   : dts -> delta -> a (w4, Ahi/Alo dead), bb (d_out)
//  4 scan_k      : h = a*h_prev + bb (wave scan, in-place on w4)
//  5 sfconv_k    : 3 dilated edge-pad dwconvs (alpha folded); y = h*Cs + xs*Ds
//  6 transpose   : (B,D,L) -> (B,L,D) into xs (xs-features dead)
//  7 ln_silu     : LayerNorm over D, * silu(z) (in-place on xs)
//  8a split y    -> Yhi/Ylo (w4 region, ypre dead)
//  8b split wout -> Ohi/Olo (xs region, y fp32 dead)
//  9 gemm_mfma<1>: out = y @ out_proj_w.T -> d_out (bb dead)

typedef __attribute__((ext_vector_type(8))) short short8;
typedef __attribute__((ext_vector_type(4))) float f32x4;

__device__ __forceinline__ void gload16(const void* g, void* l) {
  __builtin_amdgcn_global_load_lds(
      (const __attribute__((address_space(1))) void*)g,
      (__attribute__((address_space(3))) void*)l, 16, 0, 0);
}

// ---------------- fp32 -> bf16 hi/lo split (RNE both halves) ----------------
__global__ __launch_bounds__(256)
void split_k(const float* __restrict__ in, unsigned short* __restrict__ hi,
             unsigned short* __restrict__ lo, int n4)
{
  int i = blockIdx.x * 256 + threadIdx.x;
  if (i >= n4) return;
  float4 v = ((const float4*)in)[i];
  float vv[4] = {v.x, v.y, v.z, v.w};
  unsigned short h[4], l[4];
#pragma unroll
  for (int j = 0; j < 4; ++j) {
    unsigned u = __float_as_uint(vv[j]);
    unsigned uh = (u + 0x7fffu + ((u >> 16) & 1u)) & 0xffff0000u;
    h[j] = (unsigned short)(uh >> 16);
    float rem = vv[j] - __uint_as_float(uh);
    unsigned ur = __float_as_uint(rem);
    l[j] = (unsigned short)((ur + 0x7fffu + ((ur >> 16) & 1u)) >> 16);
  }
  ((ushort4*)hi)[i] = make_ushort4(h[0], h[1], h[2], h[3]);
  ((ushort4*)lo)[i] = make_ushort4(l[0], l[1], l[2], l[3]);
}

// ---------------- bf16x3 MFMA GEMM: C[m][n] = sum_k A[m][k] * W[n][k] -------
// 128x128 tile, 4 waves (2x2 of 64x64), 16x16x32 MFMA, BK=64, K=512, 3 passes.
// LDS layout: [row][128B of k], XOR-swizzled (cb ^= (row&7)<<4) via
// pre-swizzled global source (linear gload_lds dest) + swizzled ds_read.
template<int MODE> // 0: in_proj dual write (xin ch-major / z px-major), 1: px-major out
__global__ __launch_bounds__(256)
void gemm_mfma(const unsigned short* __restrict__ Ahi, const unsigned short* __restrict__ Alo,
               const unsigned short* __restrict__ Whi, const unsigned short* __restrict__ Wlo,
               float* __restrict__ o1, float* __restrict__ o2)
{
  __shared__ unsigned short sA[128 * 64];
  __shared__ unsigned short sB[128 * 64];
  const int tid = threadIdx.x;
  const int wave = tid >> 6, lane = tid & 63;
  const int m0 = blockIdx.y << 7;
  const int n0 = blockIdx.x << 7;
  const int wm = (wave & 1) << 6;
  const int wn = (wave >> 1) << 6;
  const int q16 = (lane >> 4) << 4;   // k-byte offset of this lane's quarter
  const int l15 = lane & 15;

  // staging source descriptors: chunk c covers LDS bytes [wave*4096+c*1024, +1024)
  int srow[4], scol[4];
#pragma unroll
  for (int c = 0; c < 4; ++c) {
    int o = (wave << 12) + (c << 10) + (lane << 4);
    int row = o >> 7;
    srow[c] = row;
    scol[c] = (o & 127) ^ ((row & 7) << 4);
  }

  f32x4 acc[4][4];
#pragma unroll
  for (int i = 0; i < 4; ++i)
#pragma unroll
    for (int j = 0; j < 4; ++j) acc[i][j] = (f32x4){0.f, 0.f, 0.f, 0.f};

  const char* APs[3] = {(const char*)Ahi, (const char*)Ahi, (const char*)Alo};
  const char* BPs[3] = {(const char*)Whi, (const char*)Wlo, (const char*)Whi};

  for (int pass = 0; pass < 3; ++pass) {
    const char* Ag = APs[pass];
    const char* Bg = BPs[pass];
    for (int kt = 0; kt < 8; ++kt) {
      int kb = kt << 7;                 // byte offset in row (BK=64 -> 128B)
      __syncthreads();                  // prior reads done before overwrite
#pragma unroll
      for (int c = 0; c < 4; ++c)
        gload16(Ag + (size_t)(m0 + srow[c]) * 1024 + kb + scol[c],
                (char*)sA + (wave << 12) + (c << 10));
#pragma unroll
      for (int c = 0; c < 4; ++c)
        gload16(Bg + (size_t)(n0 + srow[c]) * 1024 + kb + scol[c],
                (char*)sB + (wave << 12) + (c << 10));
      __syncthreads();                  // vmcnt drained before barrier
#pragma unroll
      for (int ks = 0; ks < 2; ++ks) {
        short8 af[4], bf[4];
#pragma unroll
        for (int i = 0; i < 4; ++i) {
          int row = wm + (i << 4) + l15;
          int cb = ((ks << 6) + q16) ^ ((row & 7) << 4);
          af[i] = *(const short8*)((const char*)sA + (row << 7) + cb);
        }
#pragma unroll
        for (int j = 0; j < 4; ++j) {
          int row = wn + (j << 4) + l15;
          int cb = ((ks << 6) + q16) ^ ((row & 7) << 4);
          bf[j] = *(const short8*)((const char*)sB + (row << 7) + cb);
        }
#pragma unroll
        for (int i = 0; i < 4; ++i)
#pragma unroll
          for (int j = 0; j < 4; ++j)
            acc[i][j] = __builtin_amdgcn_mfma_f32_16x16x32_bf16(af[i], bf[j], acc[i][j], 0, 0, 0);
      }
    }
  }

  // epilogue: C row = m0+wm+i*16+(lane>>4)*4+r, col = n0+wn+j*16+(lane&15)
  const int mb_base = m0 + wm + ((lane >> 4) << 2);
#pragma unroll
  for (int j = 0; j < 4; ++j) {
    int n = n0 + wn + (j << 4) + l15;
#pragma unroll
    for (int i = 0; i < 4; ++i) {
      int mb = mb_base + (i << 4);
      if (MODE == 0) {
        if (n < 512) {
          int b = mb >> 12, l = mb & 4095;
          *(f32x4*)&o1[((size_t)(b * 512 + n) << 12) + l] = acc[i][j];
        } else {
#pragma unroll
          for (int r = 0; r < 4; ++r)
            o2[(size_t)(mb + r) * 512 + (n - 512)] = acc[i][j][r];
        }
      } else {
#pragma unroll
        for (int r = 0; r < 4; ++r)
          o1[(size_t)(mb + r) * 512 + n] = acc[i][j][r];
      }
    }
  }
}

// ---------------- depthwise 3x3 SAME (zero pad) + bias + silu ----------------
__global__ __launch_bounds__(256)
void conv_silu_k(const float* __restrict__ xin, const float* __restrict__ w,
                 const float* __restrict__ bias, float* __restrict__ xs)
{
  __shared__ float t[64][65];
  int plane = blockIdx.x;          // b*512 + d
  int d = plane & 511;
  int tid = threadIdx.x;
  const float* src = xin + (size_t)plane * 4096;
#pragma unroll
  for (int i = 0; i < 16; i++) {
    int idx = tid + i * 256;
    t[idx >> 6][idx & 63] = src[idx];
  }
  float wv[9];
#pragma unroll
  for (int j = 0; j < 9; j++) wv[j] = w[d * 9 + j];
  float bv = bias[d];
  __syncthreads();
  float* dst = xs + (size_t)plane * 4096;
#pragma unroll
  for (int i = 0; i < 16; i++) {
    int idx = tid + i * 256;
    int y = idx >> 6, x = idx & 63;
    float s = bv;
#pragma unroll
    for (int u = 0; u < 3; u++)
#pragma unroll
      for (int v = 0; v < 3; v++) {
        int yy = y + u - 1, xx = x + v - 1;
        if (yy >= 0 && yy < 64 && xx >= 0 && xx < 64)
          s = fmaf(wv[u * 3 + v], t[yy][xx], s);
      }
    dst[idx] = s * (1.f / (1.f + __expf(-s)));   // silu
  }
}

// ------- 3a: partial x_dbl GEMM: 8-way split over d; one pixel per thread ---
__global__ __launch_bounds__(256)
void xdbl_part_k(const float* __restrict__ xs, const float* __restrict__ xpw,
                 float* __restrict__ partial)
{
  __shared__ float sw[34 * 64];    // xpw chunk, [k][dd]
  int tid = threadIdx.x;
  int p  = blockIdx.x * 256 + tid;   // pixel 0..16383 (b*4096+l)
  int d0 = blockIdx.y * 64;
  int b = p >> 12, l = p & 4095;
  for (int i = tid; i < 34 * 64; i += 256) {
    int k = i >> 6, dd = i & 63;
    sw[i] = xpw[k * 512 + d0 + dd];
  }
  __syncthreads();
  float acc[34];
#pragma unroll
  for (int k = 0; k < 34; k++) acc[k] = 0.f;
  const float* xp = xs + (size_t)(b * 512 + d0) * 4096 + l;
#pragma unroll 4
  for (int dd = 0; dd < 64; dd++) {
    float v = xp[(size_t)dd * 4096];
#pragma unroll
    for (int k = 0; k < 34; k++) acc[k] = fmaf(sw[k * 64 + dd], v, acc[k]);
  }
  float* op = partial + (size_t)blockIdx.y * 34 * 16384 + p;
#pragma unroll
  for (int k = 0; k < 34; k++) op[(size_t)k * 16384] = acc[k];
}

// ------- 3b: reduce 8 partials -> xdbl_r[34][16384] -------------------------
__global__ __launch_bounds__(256)
void xdbl_reduce_k(const float* __restrict__ partial, float* __restrict__ xdbl_r)
{
  int gid = blockIdx.x * 256 + threadIdx.x;   // 0 .. 34*16384-1
  float s = 0.f;
#pragma unroll
  for (int sp = 0; sp < 8; sp++) s += partial[(size_t)sp * 34 * 16384 + gid];
  xdbl_r[gid] = s;
}

// ------- 3c: dts -> delta -> a, bb. LDS-stage xdbl rows for a 256-px tile ---
__global__ __launch_bounds__(256)
void delta_ab_k(const float* __restrict__ xdbl_r, const float* __restrict__ xs,
                const float* __restrict__ dtw, const float* __restrict__ dtb,
                const float* __restrict__ A_logs, float* __restrict__ a_buf,
                float* __restrict__ bb_buf)
{
  __shared__ float sm[33][256];    // rows 0..31 = dt-rank, row 32 = Bs
  int tid = threadIdx.x;
  int l0 = blockIdx.x * 256;       // l tile within batch
  int d0 = blockIdx.y * 64;        // d chunk
  int b  = blockIdx.z;
  int p0 = b * 4096 + l0;
#pragma unroll
  for (int k = 0; k < 33; k++) sm[k][tid] = xdbl_r[k * 16384 + p0 + tid];
  __syncthreads();
  float Bsl = sm[32][tid];
  const float* xp = xs + (size_t)(b * 512 + d0) * 4096 + l0 + tid;
#pragma unroll 2
  for (int dd = 0; dd < 64; dd++) {
    int d = d0 + dd;
    float s = dtb[d];
#pragma unroll
    for (int r = 0; r < 32; r++) s = fmaf(dtw[d * 32 + r], sm[r][tid], s);
    float delta = fmaxf(s, 0.f) + __logf(1.f + __expf(-fabsf(s)));  // softplus
    float Ad = -__expf(A_logs[d]);
    float av = __expf(delta * Ad);
    float v = xp[(size_t)dd * 4096];
    size_t o = ((size_t)(b * 512 + d)) * 4096 + l0 + tid;
    a_buf[o] = av;
    bb_buf[o] = delta * Bsl * v;
  }
}

// ---------------- first-order scan, one wave per (b,d) row ------------------
__global__ __launch_bounds__(256)
void scan_k(float* __restrict__ a_h, const float* __restrict__ bb)
{
  int wid = threadIdx.x >> 6, lane = threadIdx.x & 63;
  int row = blockIdx.x * 4 + wid;            // 0..2047
  size_t base = (size_t)row * 4096;
  float s = 0.f;
  for (int c = 0; c < 64; c++) {
    int l = c * 64 + lane;
    float Av = a_h[base + l];
    float Bv = bb[base + l];
#pragma unroll
    for (int off = 1; off < 64; off <<= 1) {
      float Ap = __shfl_up(Av, off);
      float Bp = __shfl_up(Bv, off);
      if (lane >= off) { Bv = fmaf(Av, Bp, Bv); Av *= Ap; }
    }
    float h = fmaf(Av, s, Bv);
    a_h[base + l] = h;
    s = __shfl(h, 63);
  }
}

// ---- 3 dilated edge-pad depthwise convs (alpha folded) + y = h*Cs + xs*Ds --
__global__ __launch_bounds__(256)
void sfconv_k(float* __restrict__ h, const float* __restrict__ k1,
              const float* __restrict__ k2, const float* __restrict__ k3,
              const float* __restrict__ alpha, const float* __restrict__ Cs,
              const float* __restrict__ xs, const float* __restrict__ Ds)
{
  __shared__ float t[64][65];
  int plane = blockIdx.x;
  int d = plane & 511;
  int b = plane >> 9;
  int tid = threadIdx.x;
  float* hp = h + (size_t)plane * 4096;
#pragma unroll
  for (int i = 0; i < 16; i++) {
    int idx = tid + i * 256;
    t[idx >> 6][idx & 63] = hp[idx];
  }
  float wv[3][9];
  float a0 = alpha[0], a1 = alpha[1], a2 = alpha[2];
#pragma unroll
  for (int j = 0; j < 9; j++) {
    wv[0][j] = a0 * k1[d * 9 + j];
    wv[1][j] = a1 * k2[d * 9 + j];
    wv[2][j] = a2 * k3[d * 9 + j];
  }
  float Dv = Ds[d];
  const float* xsp = xs + (size_t)plane * 4096;
  const float* Csp = Cs + b * 4096;
  __syncthreads();
#pragma unroll
  for (int i = 0; i < 16; i++) {
    int idx = tid + i * 256;
    int y = idx >> 6, x = idx & 63;
    float s = 0.f;
#pragma unroll
    for (int dil = 1; dil <= 3; dil++)
#pragma unroll
      for (int u = 0; u < 3; u++)
#pragma unroll
        for (int v = 0; v < 3; v++) {
          int yy = y + (u - 1) * dil; yy = yy < 0 ? 0 : (yy > 63 ? 63 : yy);
          int xx = x + (v - 1) * dil; xx = xx < 0 ? 0 : (xx > 63 ? 63 : xx);
          s = fmaf(wv[dil - 1][u * 3 + v], t[yy][xx], s);
        }
    hp[idx] = fmaf(s, Csp[idx], xsp[idx] * Dv);   // in-place (reads from LDS)
  }
}

// ---------------- transpose (B,D,L) -> (B,L,D) -------------------------------
__global__ __launch_bounds__(256)
void transpose_k(const float* __restrict__ src, float* __restrict__ dst)
{
  __shared__ float t[64][65];
  int l0 = blockIdx.x * 64;
  int d0 = blockIdx.y * 64;
  int b  = blockIdx.z;
  int tid = threadIdx.x;
  int c = tid & 63, r4 = tid >> 6;
#pragma unroll
  for (int i = 0; i < 16; i++) {
    int r = r4 + i * 4;
    t[r][c] = src[((size_t)(b * 512 + d0 + r)) * 4096 + l0 + c];
  }
  __syncthreads();
#pragma unroll
  for (int i = 0; i < 16; i++) {
    int r = r4 + i * 4;   // l offset
    dst[((size_t)(b * 4096 + l0 + r)) * 512 + d0 + c] = t[c][r];
  }
}

// ---------------- LayerNorm over D + silu(z) gate (in-place) ----------------
__global__ __launch_bounds__(256)
void ln_silu_k(float* __restrict__ y, const float* __restrict__ z,
               const float* __restrict__ lw, const float* __restrict__ lb)
{
  int wid = threadIdx.x >> 6, lane = threadIdx.x & 63;
  int pix = blockIdx.x * 4 + wid;            // 0..16383
  float* yp = y + (size_t)pix * 512;
  const float* zp = z + (size_t)pix * 512;
  float4 v0 = *(float4*)&yp[lane * 8];
  float4 v1 = *(float4*)&yp[lane * 8 + 4];
  float vv[8] = {v0.x,v0.y,v0.z,v0.w,v1.x,v1.y,v1.z,v1.w};
  float sum = 0.f;
#pragma unroll
  for (int j = 0; j < 8; j++) sum += vv[j];
#pragma unroll
  for (int off = 1; off < 64; off <<= 1) sum += __shfl_xor(sum, off);
  float mu = sum * (1.f / 512.f);
  float q = 0.f;
#pragma unroll
  for (int j = 0; j < 8; j++) { float dd = vv[j] - mu; q += dd * dd; }
#pragma unroll
  for (int off = 1; off < 64; off <<= 1) q += __shfl_xor(q, off);
  float rstd = rsqrtf(q * (1.f / 512.f) + 1e-5f);
  float4 z0 = *(const float4*)&zp[lane * 8];
  float4 z1 = *(const float4*)&zp[lane * 8 + 4];
  float zz[8] = {z0.x,z0.y,z0.z,z0.w,z1.x,z1.y,z1.z,z1.w};
  float out[8];
#pragma unroll
  for (int j = 0; j < 8; j++) {
    int dch = lane * 8 + j;
    float val = (vv[j] - mu) * rstd * lw[dch] + lb[dch];
    float zv = zz[j];
    out[j] = val * (zv * (1.f / (1.f + __expf(-zv))));
  }
  *(float4*)&yp[lane * 8]     = make_float4(out[0], out[1], out[2], out[3]);
  *(float4*)&yp[lane * 8 + 4] = make_float4(out[4], out[5], out[6], out[7]);
}

extern "C" void kernel_launch(void* const* d_in, const int* in_sizes, int n_in,
                              void* d_out, int out_size, void* d_ws, size_t ws_size,
                              hipStream_t stream)
{
  const float* x    = (const float*)d_in[0];
  const float* win  = (const float*)d_in[1];
  const float* cw   = (const float*)d_in[2];
  const float* cb   = (const float*)d_in[3];
  const float* xpw  = (const float*)d_in[4];
  const float* dtw  = (const float*)d_in[5];
  const float* dtb  = (const float*)d_in[6];
  const float* alog = (const float*)d_in[7];
  const float* Dsv  = (const float*)d_in[8];
  const float* k1   = (const float*)d_in[9];
  const float* k2   = (const float*)d_in[10];
  const float* k3   = (const float*)d_in[11];
  const float* alp  = (const float*)d_in[12];
  const float* lw   = (const float*)d_in[13];
  const float* lb   = (const float*)d_in[14];
  const float* wout = (const float*)d_in[15];
  float* out = (float*)d_out;

  const size_t NP = (size_t)4 * 512 * 4096;   // 8,388,608 elems per (B,D,L) buffer
  float* ws = (float*)d_ws;
  float* xs     = ws;                 // xs features; later y_t; overlays Whi/Wlo, Ohi/Olo
  float* zb     = ws + NP;            // z, pixel-major
  float* w4     = ws + 2 * NP;        // overlays Ahi/Alo; then a/h/ypre; then Yhi/Ylo
  float* xdbl_r = ws + 3 * NP;        // 34 x 16384

  unsigned short* Ahi = (unsigned short*)w4;          // 16384x512 bf16
  unsigned short* Alo = Ahi + (size_t)16384 * 512;    // fills w4 region exactly
  unsigned short* Whi = (unsigned short*)xs;          // 1024x512 bf16
  unsigned short* Wlo = Whi + (size_t)1024 * 512;
  unsigned short* Yhi = Ahi;                          // reuse after ypre dead
  unsigned short* Ylo = Alo;
  unsigned short* Ohi = (unsigned short*)xs;          // 512x512 bf16 (after xs dead)
  unsigned short* Olo = Ohi + (size_t)512 * 512;

  split_k<<<8192, 256, 0, stream>>>(x, Ahi, Alo, 2097152);                  // x -> hi/lo
  split_k<<<512, 256, 0, stream>>>(win, Whi, Wlo, 131072);                  // win -> hi/lo
  gemm_mfma<0><<<dim3(8, 128), 256, 0, stream>>>(Ahi, Alo, Whi, Wlo, out, zb);
  conv_silu_k<<<2048, 256, 0, stream>>>(out, cw, cb, xs);                   // xs
  xdbl_part_k<<<dim3(64, 8), 256, 0, stream>>>(xs, xpw, out);               // partial->d_out
  xdbl_reduce_k<<<2176, 256, 0, stream>>>(out, xdbl_r);                     // xdbl_r
  delta_ab_k<<<dim3(16, 8, 4), 256, 0, stream>>>(xdbl_r, xs, dtw, dtb, alog,
                                                 w4, out);                  // a->w4, bb->d_out
  scan_k<<<512, 256, 0, stream>>>(w4, out);                                 // h in w4
  sfconv_k<<<2048, 256, 0, stream>>>(w4, k1, k2, k3, alp,
                                     xdbl_r + 33 * 16384, xs, Dsv);         // ypre in w4
  transpose_k<<<dim3(64, 8, 4), 256, 0, stream>>>(w4, xs);                  // y_t -> xs
  ln_silu_k<<<4096, 256, 0, stream>>>(xs, zb, lw, lb);                      // in-place
  split_k<<<8192, 256, 0, stream>>>(xs, Yhi, Ylo, 2097152);                 // y -> hi/lo
  split_k<<<256, 256, 0, stream>>>(wout, Ohi, Olo, 65536);                  // wout -> hi/lo
  gemm_mfma<1><<<dim3(4, 128), 256, 0, stream>>>(Yhi, Ylo, Ohi, Olo, out, nullptr);
}

// Round 4
// 251.074 us; speedup vs baseline: 4.1459x; 1.1821x over previous
//
#include <hip/hip_runtime.h>
#include <cstddef>

// B=4, L=4096 (=64x64), d_model=512, d_inner=512, dt_rank=32, d_state=1
// GEMMs on MFMA via bf16x3 split (hi*hi + hi*lo + lo*hi), fp32 accum,
// kt-outer staging of all 4 panels + bijective XCD-chunked block swizzle.
// Fusions: scan+sfconv (h stays in LDS), ln_silu+split_y (writes bf16 hi/lo).

typedef __attribute__((ext_vector_type(8))) short short8;
typedef __attribute__((ext_vector_type(4))) float f32x4;

__device__ __forceinline__ void gload16(const void* g, void* l) {
  __builtin_amdgcn_global_load_lds(
      (const __attribute__((address_space(1))) void*)g,
      (__attribute__((address_space(3))) void*)l, 16, 0, 0);
}

__device__ __forceinline__ void bf16split(float v, unsigned short& h, unsigned short& l) {
  unsigned u = __float_as_uint(v);
  unsigned uh = (u + 0x7fffu + ((u >> 16) & 1u)) & 0xffff0000u;
  h = (unsigned short)(uh >> 16);
  float rem = v - __uint_as_float(uh);
  unsigned ur = __float_as_uint(rem);
  l = (unsigned short)((ur + 0x7fffu + ((ur >> 16) & 1u)) >> 16);
}

// ---------------- fp32 -> bf16 hi/lo split ----------------------------------
__global__ __launch_bounds__(256)
void split_k(const float* __restrict__ in, unsigned short* __restrict__ hi,
             unsigned short* __restrict__ lo, int n4)
{
  int i = blockIdx.x * 256 + threadIdx.x;
  if (i >= n4) return;
  float4 v = ((const float4*)in)[i];
  float vv[4] = {v.x, v.y, v.z, v.w};
  unsigned short h[4], l[4];
#pragma unroll
  for (int j = 0; j < 4; ++j) bf16split(vv[j], h[j], l[j]);
  ((ushort4*)hi)[i] = make_ushort4(h[0], h[1], h[2], h[3]);
  ((ushort4*)lo)[i] = make_ushort4(l[0], l[1], l[2], l[3]);
}

// ---------------- bf16x3 MFMA GEMM: C[m][n] = sum_k A[m][k] * W[n][k] -------
// 128x128 tile, 4 waves (2x2 of 64x64), 16x16x32 MFMA, BK=64, K=512.
// kt-outer: per K-step stage Ahi/Alo/Whi/Wlo (64 KB LDS), 3 combos inner.
// XOR-swizzled LDS (cb ^= (row&7)<<4) via pre-swizzled global source.
template<int MODE> // 0: in_proj dual write (xin ch-major / z px-major), 1: px-major out
__global__ __launch_bounds__(256)
void gemm_mfma(const unsigned short* __restrict__ Ahi, const unsigned short* __restrict__ Alo,
               const unsigned short* __restrict__ Whi, const unsigned short* __restrict__ Wlo,
               float* __restrict__ o1, float* __restrict__ o2)
{
  __shared__ unsigned short sAh[128 * 64];
  __shared__ unsigned short sAl[128 * 64];
  __shared__ unsigned short sBh[128 * 64];
  __shared__ unsigned short sBl[128 * 64];
  const int tid = threadIdx.x;
  const int wave = tid >> 6, lane = tid & 63;

  // bijective XCD-chunked swizzle (nwg % 8 == 0 here, formula general)
  const int nwg = gridDim.x;
  const int q = nwg >> 3, r = nwg & 7;
  const int xcd = blockIdx.x & 7, wi = blockIdx.x >> 3;
  const int logical = (xcd < r ? xcd * (q + 1) : r * (q + 1) + (xcd - r) * q) + wi;
  const int NTN = (MODE == 0) ? 8 : 4;
  const int tm = logical / NTN, tn = logical - tm * NTN;
  const int m0 = tm << 7, n0 = tn << 7;

  const int wm = (wave & 1) << 6;
  const int wn = (wave >> 1) << 6;
  const int q16 = (lane >> 4) << 4;
  const int l15 = lane & 15;

  int srow[4], scol[4];
#pragma unroll
  for (int c = 0; c < 4; ++c) {
    int o = (wave << 12) + (c << 10) + (lane << 4);
    int row = o >> 7;
    srow[c] = row;
    scol[c] = (o & 127) ^ ((row & 7) << 4);
  }

  f32x4 acc[4][4];
#pragma unroll
  for (int i = 0; i < 4; ++i)
#pragma unroll
    for (int j = 0; j < 4; ++j) acc[i][j] = (f32x4){0.f, 0.f, 0.f, 0.f};

  for (int kt = 0; kt < 8; ++kt) {
    int kb = kt << 7;
    __syncthreads();
#pragma unroll
    for (int c = 0; c < 4; ++c) {
      size_t ga = (size_t)(m0 + srow[c]) * 1024 + kb + scol[c];
      size_t gb = (size_t)(n0 + srow[c]) * 1024 + kb + scol[c];
      int lo_ = (wave << 12) + (c << 10);
      gload16((const char*)Ahi + ga, (char*)sAh + lo_);
      gload16((const char*)Alo + ga, (char*)sAl + lo_);
      gload16((const char*)Whi + gb, (char*)sBh + lo_);
      gload16((const char*)Wlo + gb, (char*)sBl + lo_);
    }
    __syncthreads();
#pragma unroll
    for (int ks = 0; ks < 2; ++ks) {
      short8 ah[4], al[4], bh[4], bl[4];
#pragma unroll
      for (int i = 0; i < 4; ++i) {
        int row = wm + (i << 4) + l15;
        int cb = ((ks << 6) + q16) ^ ((row & 7) << 4);
        ah[i] = *(const short8*)((const char*)sAh + (row << 7) + cb);
        al[i] = *(const short8*)((const char*)sAl + (row << 7) + cb);
      }
#pragma unroll
      for (int j = 0; j < 4; ++j) {
        int row = wn + (j << 4) + l15;
        int cb = ((ks << 6) + q16) ^ ((row & 7) << 4);
        bh[j] = *(const short8*)((const char*)sBh + (row << 7) + cb);
        bl[j] = *(const short8*)((const char*)sBl + (row << 7) + cb);
      }
#pragma unroll
      for (int i = 0; i < 4; ++i)
#pragma unroll
        for (int j = 0; j < 4; ++j) {
          acc[i][j] = __builtin_amdgcn_mfma_f32_16x16x32_bf16(ah[i], bh[j], acc[i][j], 0, 0, 0);
          acc[i][j] = __builtin_amdgcn_mfma_f32_16x16x32_bf16(ah[i], bl[j], acc[i][j], 0, 0, 0);
          acc[i][j] = __builtin_amdgcn_mfma_f32_16x16x32_bf16(al[i], bh[j], acc[i][j], 0, 0, 0);
        }
    }
  }

  const int mb_base = m0 + wm + ((lane >> 4) << 2);
#pragma unroll
  for (int j = 0; j < 4; ++j) {
    int n = n0 + wn + (j << 4) + l15;
#pragma unroll
    for (int i = 0; i < 4; ++i) {
      int mb = mb_base + (i << 4);
      if (MODE == 0) {
        if (n < 512) {
          int b = mb >> 12, l = mb & 4095;
          *(f32x4*)&o1[((size_t)(b * 512 + n) << 12) + l] = acc[i][j];
        } else {
#pragma unroll
          for (int rr = 0; rr < 4; ++rr)
            o2[(size_t)(mb + rr) * 512 + (n - 512)] = acc[i][j][rr];
        }
      } else {
#pragma unroll
        for (int rr = 0; rr < 4; ++rr)
          o1[(size_t)(mb + rr) * 512 + n] = acc[i][j][rr];
      }
    }
  }
}

// ---------------- depthwise 3x3 SAME (zero pad) + bias + silu ----------------
__global__ __launch_bounds__(256)
void conv_silu_k(const float* __restrict__ xin, const float* __restrict__ w,
                 const float* __restrict__ bias, float* __restrict__ xs)
{
  __shared__ float t[64][65];
  int plane = blockIdx.x;          // b*512 + d
  int d = plane & 511;
  int tid = threadIdx.x;
  const float* src = xin + (size_t)plane * 4096;
#pragma unroll
  for (int i = 0; i < 16; i++) {
    int idx = tid + i * 256;
    t[idx >> 6][idx & 63] = src[idx];
  }
  float wv[9];
#pragma unroll
  for (int j = 0; j < 9; j++) wv[j] = w[d * 9 + j];
  float bv = bias[d];
  __syncthreads();
  float* dst = xs + (size_t)plane * 4096;
#pragma unroll
  for (int i = 0; i < 16; i++) {
    int idx = tid + i * 256;
    int y = idx >> 6, x = idx & 63;
    float s = bv;
#pragma unroll
    for (int u = 0; u < 3; u++)
#pragma unroll
      for (int v = 0; v < 3; v++) {
        int yy = y + u - 1, xx = x + v - 1;
        if (yy >= 0 && yy < 64 && xx >= 0 && xx < 64)
          s = fmaf(wv[u * 3 + v], t[yy][xx], s);
      }
    dst[idx] = s * (1.f / (1.f + __expf(-s)));   // silu
  }
}

// ------- 3a: partial x_dbl GEMM: 8-way split over d; one pixel per thread ---
__global__ __launch_bounds__(256)
void xdbl_part_k(const float* __restrict__ xs, const float* __restrict__ xpw,
                 float* __restrict__ partial)
{
  __shared__ float sw[34 * 64];    // xpw chunk, [k][dd]
  int tid = threadIdx.x;
  int p  = blockIdx.x * 256 + tid;   // pixel 0..16383 (b*4096+l)
  int d0 = blockIdx.y * 64;
  int b = p >> 12, l = p & 4095;
  for (int i = tid; i < 34 * 64; i += 256) {
    int k = i >> 6, dd = i & 63;
    sw[i] = xpw[k * 512 + d0 + dd];
  }
  __syncthreads();
  float acc[34];
#pragma unroll
  for (int k = 0; k < 34; k++) acc[k] = 0.f;
  const float* xp = xs + (size_t)(b * 512 + d0) * 4096 + l;
#pragma unroll 4
  for (int dd = 0; dd < 64; dd++) {
    float v = xp[(size_t)dd * 4096];
#pragma unroll
    for (int k = 0; k < 34; k++) acc[k] = fmaf(sw[k * 64 + dd], v, acc[k]);
  }
  float* op = partial + (size_t)blockIdx.y * 34 * 16384 + p;
#pragma unroll
  for (int k = 0; k < 34; k++) op[(size_t)k * 16384] = acc[k];
}

// ------- 3b: reduce 8 partials -> xdbl_r[34][16384] -------------------------
__global__ __launch_bounds__(256)
void xdbl_reduce_k(const float* __restrict__ partial, float* __restrict__ xdbl_r)
{
  int gid = blockIdx.x * 256 + threadIdx.x;   // 0 .. 34*16384-1
  float s = 0.f;
#pragma unroll
  for (int sp = 0; sp < 8; sp++) s += partial[(size_t)sp * 34 * 16384 + gid];
  xdbl_r[gid] = s;
}

// ------- 3c: dts -> delta -> a, bb. LDS-stage xdbl rows for a 256-px tile ---
__global__ __launch_bounds__(256)
void delta_ab_k(const float* __restrict__ xdbl_r, const float* __restrict__ xs,
                const float* __restrict__ dtw, const float* __restrict__ dtb,
                const float* __restrict__ A_logs, float* __restrict__ a_buf,
                float* __restrict__ bb_buf)
{
  __shared__ float sm[33][256];    // rows 0..31 = dt-rank, row 32 = Bs
  int tid = threadIdx.x;
  int l0 = blockIdx.x * 256;       // l tile within batch
  int d0 = blockIdx.y * 64;        // d chunk
  int b  = blockIdx.z;
  int p0 = b * 4096 + l0;
#pragma unroll
  for (int k = 0; k < 33; k++) sm[k][tid] = xdbl_r[k * 16384 + p0 + tid];
  __syncthreads();
  float Bsl = sm[32][tid];
  const float* xp = xs + (size_t)(b * 512 + d0) * 4096 + l0 + tid;
#pragma unroll 2
  for (int dd = 0; dd < 64; dd++) {
    int d = d0 + dd;
    float s = dtb[d];
#pragma unroll
    for (int r = 0; r < 32; r++) s = fmaf(dtw[d * 32 + r], sm[r][tid], s);
    float delta = fmaxf(s, 0.f) + __logf(1.f + __expf(-fabsf(s)));  // softplus
    float Ad = -__expf(A_logs[d]);
    float av = __expf(delta * Ad);
    float v = xp[(size_t)dd * 4096];
    size_t o = ((size_t)(b * 512 + d)) * 4096 + l0 + tid;
    a_buf[o] = av;
    bb_buf[o] = delta * Bsl * v;
  }
}

// ---- fused: block scan over plane (4 waves x 1024 segments) + dilated convs
// h stays in LDS; ypre written in-place over the a buffer.
__global__ __launch_bounds__(256)
void scan_sfconv_k(float* __restrict__ a_buf, const float* __restrict__ bb,
                   const float* __restrict__ k1, const float* __restrict__ k2,
                   const float* __restrict__ k3, const float* __restrict__ alpha,
                   const float* __restrict__ Cs, const float* __restrict__ xs,
                   const float* __restrict__ Ds)
{
  __shared__ float t[64][65];      // h (local scan, then global h)
  __shared__ float u[64][65];      // cumulative A from segment start
  __shared__ float segA[4], segH[4];
  int plane = blockIdx.x;
  int d = plane & 511;
  int b = plane >> 9;
  int tid = threadIdx.x;
  int wave = tid >> 6, lane = tid & 63;
  size_t base = (size_t)plane * 4096;

  // phase 1: per-wave segment scan (segment = 1024 elements, 16 chunks of 64)
  float ca = 1.f, ch = 0.f;
  for (int c = 0; c < 16; ++c) {
    int l = wave * 1024 + c * 64 + lane;
    float Av = a_buf[base + l];
    float Bv = bb[base + l];
#pragma unroll
    for (int off = 1; off < 64; off <<= 1) {
      float Ap = __shfl_up(Av, off);
      float Bp = __shfl_up(Bv, off);
      if (lane >= off) { Bv = fmaf(Av, Bp, Bv); Av *= Ap; }
    }
    float h  = fmaf(Av, ch, Bv);   // h relative to segment start (h_in = 0)
    float ac = Av * ca;            // cumulative a-product from segment start
    t[l >> 6][l & 63] = h;
    u[l >> 6][l & 63] = ac;
    ch = __shfl(h, 63);
    ca = __shfl(ac, 63);
  }
  if (lane == 0) { segA[wave] = ca; segH[wave] = ch; }
  __syncthreads();

  // phase 2: segment carries (all threads compute identically)
  float cy1 = segH[0];
  float cy2 = fmaf(segA[1], cy1, segH[1]);
  float cy3 = fmaf(segA[2], cy2, segH[2]);
  float myc = (wave == 1) ? cy1 : (wave == 2) ? cy2 : (wave == 3) ? cy3 : 0.f;

  // phase 3: apply carry
  if (wave > 0) {
    for (int c = 0; c < 16; ++c) {
      int l = wave * 1024 + c * 64 + lane;
      t[l >> 6][l & 63] = fmaf(u[l >> 6][l & 63], myc, t[l >> 6][l & 63]);
    }
  }
  __syncthreads();

  // phase 4: 3 dilated edge-pad convs from LDS + y = conv*Cs + xs*Ds
  float wv[3][9];
  float a0 = alpha[0], a1 = alpha[1], a2 = alpha[2];
#pragma unroll
  for (int j = 0; j < 9; j++) {
    wv[0][j] = a0 * k1[d * 9 + j];
    wv[1][j] = a1 * k2[d * 9 + j];
    wv[2][j] = a2 * k3[d * 9 + j];
  }
  float Dv = Ds[d];
  const float* xsp = xs + base;
  const float* Csp = Cs + b * 4096;
  float* yp = a_buf + base;        // in-place (a consumed in phase 1)
#pragma unroll
  for (int i = 0; i < 16; i++) {
    int idx = tid + i * 256;
    int y = idx >> 6, x = idx & 63;
    float s = 0.f;
#pragma unroll
    for (int dil = 1; dil <= 3; dil++)
#pragma unroll
      for (int uu = 0; uu < 3; uu++)
#pragma unroll
        for (int vv = 0; vv < 3; vv++) {
          int yy = y + (uu - 1) * dil; yy = yy < 0 ? 0 : (yy > 63 ? 63 : yy);
          int xx = x + (vv - 1) * dil; xx = xx < 0 ? 0 : (xx > 63 ? 63 : xx);
          s = fmaf(wv[dil - 1][uu * 3 + vv], t[yy][xx], s);
        }
    yp[idx] = fmaf(s, Csp[idx], xsp[idx] * Dv);
  }
}

// ---------------- transpose (B,D,L) -> (B,L,D) -------------------------------
__global__ __launch_bounds__(256)
void transpose_k(const float* __restrict__ src, float* __restrict__ dst)
{
  __shared__ float t[64][65];
  int l0 = blockIdx.x * 64;
  int d0 = blockIdx.y * 64;
  int b  = blockIdx.z;
  int tid = threadIdx.x;
  int c = tid & 63, r4 = tid >> 6;
#pragma unroll
  for (int i = 0; i < 16; i++) {
    int r = r4 + i * 4;
    t[r][c] = src[((size_t)(b * 512 + d0 + r)) * 4096 + l0 + c];
  }
  __syncthreads();
#pragma unroll
  for (int i = 0; i < 16; i++) {
    int r = r4 + i * 4;   // l offset
    dst[((size_t)(b * 4096 + l0 + r)) * 512 + d0 + c] = t[c][r];
  }
}

// -------- LayerNorm over D + silu(z) gate, writes bf16 hi/lo directly -------
__global__ __launch_bounds__(256)
void ln_silu_split_k(const float* __restrict__ y, const float* __restrict__ z,
                     const float* __restrict__ lw, const float* __restrict__ lb,
                     unsigned short* __restrict__ hi, unsigned short* __restrict__ lo)
{
  int wid = threadIdx.x >> 6, lane = threadIdx.x & 63;
  int pix = blockIdx.x * 4 + wid;            // 0..16383
  const float* yp = y + (size_t)pix * 512;
  const float* zp = z + (size_t)pix * 512;
  float4 v0 = *(const float4*)&yp[lane * 8];
  float4 v1 = *(const float4*)&yp[lane * 8 + 4];
  float vv[8] = {v0.x,v0.y,v0.z,v0.w,v1.x,v1.y,v1.z,v1.w};
  float sum = 0.f;
#pragma unroll
  for (int j = 0; j < 8; j++) sum += vv[j];
#pragma unroll
  for (int off = 1; off < 64; off <<= 1) sum += __shfl_xor(sum, off);
  float mu = sum * (1.f / 512.f);
  float q = 0.f;
#pragma unroll
  for (int j = 0; j < 8; j++) { float dd = vv[j] - mu; q += dd * dd; }
#pragma unroll
  for (int off = 1; off < 64; off <<= 1) q += __shfl_xor(q, off);
  float rstd = rsqrtf(q * (1.f / 512.f) + 1e-5f);
  float4 z0 = *(const float4*)&zp[lane * 8];
  float4 z1 = *(const float4*)&zp[lane * 8 + 4];
  float zz[8] = {z0.x,z0.y,z0.z,z0.w,z1.x,z1.y,z1.z,z1.w};
  unsigned short oh[8], ol[8];
#pragma unroll
  for (int j = 0; j < 8; j++) {
    int dch = lane * 8 + j;
    float val = (vv[j] - mu) * rstd * lw[dch] + lb[dch];
    float zv = zz[j];
    float ov = val * (zv * (1.f / (1.f + __expf(-zv))));
    bf16split(ov, oh[j], ol[j]);
  }
  size_t o = (size_t)pix * 512 + lane * 8;
  *(ushort4*)&hi[o]     = make_ushort4(oh[0], oh[1], oh[2], oh[3]);
  *(ushort4*)&hi[o + 4] = make_ushort4(oh[4], oh[5], oh[6], oh[7]);
  *(ushort4*)&lo[o]     = make_ushort4(ol[0], ol[1], ol[2], ol[3]);
  *(ushort4*)&lo[o + 4] = make_ushort4(ol[4], ol[5], ol[6], ol[7]);
}

extern "C" void kernel_launch(void* const* d_in, const int* in_sizes, int n_in,
                              void* d_out, int out_size, void* d_ws, size_t ws_size,
                              hipStream_t stream)
{
  const float* x    = (const float*)d_in[0];
  const float* win  = (const float*)d_in[1];
  const float* cw   = (const float*)d_in[2];
  const float* cb   = (const float*)d_in[3];
  const float* xpw  = (const float*)d_in[4];
  const float* dtw  = (const float*)d_in[5];
  const float* dtb  = (const float*)d_in[6];
  const float* alog = (const float*)d_in[7];
  const float* Dsv  = (const float*)d_in[8];
  const float* k1   = (const float*)d_in[9];
  const float* k2   = (const float*)d_in[10];
  const float* k3   = (const float*)d_in[11];
  const float* alp  = (const float*)d_in[12];
  const float* lw   = (const float*)d_in[13];
  const float* lb   = (const float*)d_in[14];
  const float* wout = (const float*)d_in[15];
  float* out = (float*)d_out;

  const size_t NP = (size_t)4 * 512 * 4096;   // 8,388,608 elems per (B,D,L) buffer
  float* ws = (float*)d_ws;
  float* xs     = ws;                 // xs features; later y_t; overlays Whi/Wlo, Ohi/Olo
  float* zb     = ws + NP;            // z, pixel-major
  float* w4     = ws + 2 * NP;        // overlays Ahi/Alo; then a/h/ypre; then Yhi/Ylo
  float* xdbl_r = ws + 3 * NP;        // 34 x 16384

  unsigned short* Ahi = (unsigned short*)w4;          // 16384x512 bf16
  unsigned short* Alo = Ahi + (size_t)16384 * 512;    // fills w4 region exactly
  unsigned short* Whi = (unsigned short*)xs;          // 1024x512 bf16
  unsigned short* Wlo = Whi + (size_t)1024 * 512;
  unsigned short* Yhi = Ahi;                          // reuse after ypre dead
  unsigned short* Ylo = Alo;
  unsigned short* Ohi = (unsigned short*)xs;          // 512x512 bf16 (after y_t read)
  unsigned short* Olo = Ohi + (size_t)512 * 512;

  split_k<<<8192, 256, 0, stream>>>(x, Ahi, Alo, 2097152);                  // x -> hi/lo
  split_k<<<512, 256, 0, stream>>>(win, Whi, Wlo, 131072);                  // win -> hi/lo
  gemm_mfma<0><<<1024, 256, 0, stream>>>(Ahi, Alo, Whi, Wlo, out, zb);      // xin, z
  conv_silu_k<<<2048, 256, 0, stream>>>(out, cw, cb, xs);                   // xs
  xdbl_part_k<<<dim3(64, 8), 256, 0, stream>>>(xs, xpw, out);               // partial->d_out
  xdbl_reduce_k<<<2176, 256, 0, stream>>>(out, xdbl_r);                     // xdbl_r
  delta_ab_k<<<dim3(16, 8, 4), 256, 0, stream>>>(xdbl_r, xs, dtw, dtb, alog,
                                                 w4, out);                  // a->w4, bb->d_out
  scan_sfconv_k<<<2048, 256, 0, stream>>>(w4, out, k1, k2, k3, alp,
                                          xdbl_r + 33 * 16384, xs, Dsv);    // ypre in w4
  transpose_k<<<dim3(64, 8, 4), 256, 0, stream>>>(w4, xs);                  // y_t -> xs
  ln_silu_split_k<<<4096, 256, 0, stream>>>(xs, zb, lw, lb, Yhi, Ylo);      // y -> bf16 hi/lo
  split_k<<<256, 256, 0, stream>>>(wout, Ohi, Olo, 65536);                  // wout -> hi/lo
  gemm_mfma<1><<<512, 256, 0, stream>>>(Yhi, Ylo, Ohi, Olo, out, nullptr);  // final
}